// Round 2
// baseline (5388.943 us; speedup 1.0000x reference)
//
#include <hip/hip_runtime.h>

#define NA_ 131072
#define NW_ 131072
#define NN  262144
#define EE  1048576
#define RR  4
#define HH  128
#define EPS_ 1e-5f

typedef unsigned short ushort_t;
typedef unsigned int uint_t;

__device__ __forceinline__ float bf2f(uint_t u16) {
    return __uint_as_float(u16 << 16);
}
__device__ __forceinline__ ushort_t f2bf(float f) {
    uint_t x = __float_as_uint(f);
    uint_t r = (x + 0x7fffu + ((x >> 16) & 1u)) >> 16;   // RNE
    return (ushort_t)r;
}

// ---------------------------------------------------------------------------
// GEMM: C[M x 128] = opt_relu(A[M x K] @ B[K x 128] (+ bias))
// A: fp32 or bf16 (A_BF). C: fp32 or bf16 (OUT_BF). B/bias: fp32.
// grid.x = M/128, block = 256 (16x16 thread tile, 8x8 outputs/thread), BK=8
// ---------------------------------------------------------------------------
template<int K, bool A_BF, bool OUT_BF, bool BIAS, bool RELU>
__global__ __launch_bounds__(256) void gemm128(const void* __restrict__ Av,
                                               const float* __restrict__ B,
                                               const float* __restrict__ bias,
                                               void* __restrict__ Cv) {
    __shared__ float As[8][128];   // [k][row]
    __shared__ float Bs[8][128];   // [k][col]
    const int tid = threadIdx.x;
    const int tx = tid & 15;
    const int ty = tid >> 4;
    const size_t blockRow = (size_t)blockIdx.x * 128;

    float acc[8][8];
    #pragma unroll
    for (int i = 0; i < 8; i++)
        #pragma unroll
        for (int j = 0; j < 8; j++) acc[i][j] = 0.f;

    const int arow = tid >> 1;           // 0..127
    const int asub = (tid & 1) * 4;      // 0 or 4
    const int brow = tid >> 5;           // 0..7
    const int bcol = (tid & 31) * 4;     // 0..124

    for (int kc = 0; kc < K; kc += 8) {
        float a4[4];
        if (A_BF) {
            const ushort_t* A = (const ushort_t*)Av;
            uint2 u = *(const uint2*)(A + (blockRow + arow) * K + kc + asub);
            a4[0] = bf2f(u.x & 0xffffu); a4[1] = bf2f(u.x >> 16);
            a4[2] = bf2f(u.y & 0xffffu); a4[3] = bf2f(u.y >> 16);
        } else {
            const float* A = (const float*)Av;
            float4 v = *(const float4*)(A + (blockRow + arow) * K + kc + asub);
            a4[0] = v.x; a4[1] = v.y; a4[2] = v.z; a4[3] = v.w;
        }
        float4 bv = *(const float4*)(B + (size_t)(kc + brow) * 128 + bcol);
        __syncthreads();
        As[asub + 0][arow] = a4[0];
        As[asub + 1][arow] = a4[1];
        As[asub + 2][arow] = a4[2];
        As[asub + 3][arow] = a4[3];
        *(float4*)(&Bs[brow][bcol]) = bv;
        __syncthreads();
        #pragma unroll
        for (int k = 0; k < 8; k++) {
            float4 a0 = *(const float4*)(&As[k][ty * 8]);
            float4 a1 = *(const float4*)(&As[k][ty * 8 + 4]);
            float4 b0 = *(const float4*)(&Bs[k][tx * 8]);
            float4 b1 = *(const float4*)(&Bs[k][tx * 8 + 4]);
            float ar[8] = {a0.x, a0.y, a0.z, a0.w, a1.x, a1.y, a1.z, a1.w};
            float br[8] = {b0.x, b0.y, b0.z, b0.w, b1.x, b1.y, b1.z, b1.w};
            #pragma unroll
            for (int i = 0; i < 8; i++)
                #pragma unroll
                for (int j = 0; j < 8; j++) acc[i][j] += ar[i] * br[j];
        }
    }

    #pragma unroll
    for (int i = 0; i < 8; i++) {
        size_t row = blockRow + ty * 8 + i;
        float t[8];
        #pragma unroll
        for (int j = 0; j < 8; j++) {
            float v = acc[i][j];
            if (BIAS) v += bias[tx * 8 + j];
            if (RELU) v = fmaxf(v, 0.f);
            t[j] = v;
        }
        if (OUT_BF) {
            ushort_t* C = (ushort_t*)Cv;
            uint4 u;
            u.x = (uint_t)f2bf(t[0]) | ((uint_t)f2bf(t[1]) << 16);
            u.y = (uint_t)f2bf(t[2]) | ((uint_t)f2bf(t[3]) << 16);
            u.z = (uint_t)f2bf(t[4]) | ((uint_t)f2bf(t[5]) << 16);
            u.w = (uint_t)f2bf(t[6]) | ((uint_t)f2bf(t[7]) << 16);
            *(uint4*)(C + row * 128 + tx * 8) = u;
        } else {
            float* C = (float*)Cv;
            *(float4*)(C + row * 128 + tx * 8) = make_float4(t[0], t[1], t[2], t[3]);
            *(float4*)(C + row * 128 + tx * 8 + 4) = make_float4(t[4], t[5], t[6], t[7]);
        }
    }
}

// ---------------------------------------------------------------------------
__global__ void count_edges(const int* __restrict__ dstv,
                            const int* __restrict__ et,
                            int* __restrict__ cnt) {
    int e = blockIdx.x * 256 + threadIdx.x;
    if (e < EE) atomicAdd(&cnt[(size_t)et[e] * NN + dstv[e]], 1);
}

__global__ void make_inv(const int* __restrict__ cnt, float* __restrict__ inv) {
    int i = blockIdx.x * 256 + threadIdx.x;
    if (i < RR * NN) {
        int c = cnt[i];
        inv[i] = 1.0f / (float)(c > 1 ? c : 1);
    }
}

// ---------------------------------------------------------------------------
// out[dst] += y[src - row_lo] * inv[r][dst] for edges with type r, src in range
// 32 lanes per edge (float4 each), 8 edges per 256-thread block
// ---------------------------------------------------------------------------
__global__ __launch_bounds__(256) void scatter_rel(const int* __restrict__ src,
                                                   const int* __restrict__ dstv,
                                                   const int* __restrict__ et,
                                                   const float* __restrict__ y,
                                                   const float* __restrict__ inv,
                                                   float* __restrict__ out,
                                                   int r, int row_lo, int row_hi) {
    int e = blockIdx.x * 8 + (threadIdx.x >> 5);
    int lane = threadIdx.x & 31;
    int s = src[e];
    if (et[e] != r || s < row_lo || s >= row_hi) return;
    int d = dstv[e];
    float w = inv[(size_t)r * NN + d];
    float4 v = ((const float4*)(y + (size_t)(s - row_lo) * 128))[lane];
    float* o = out + (size_t)d * 128 + lane * 4;
    atomicAdd(o + 0, v.x * w);
    atomicAdd(o + 1, v.y * w);
    atomicAdd(o + 2, v.z * w);
    atomicAdd(o + 3, v.w * w);
}

// ---------------------------------------------------------------------------
// LayerNorm + affine + ReLU; fp32 in, bf16 out. One 64-lane wave per node.
// ---------------------------------------------------------------------------
__global__ __launch_bounds__(256) void ln_relu(const float* __restrict__ X,
                                               const float* __restrict__ g,
                                               const float* __restrict__ b,
                                               ushort_t* __restrict__ Hout) {
    int node = blockIdx.x * 4 + (threadIdx.x >> 6);
    int lane = threadIdx.x & 63;
    float2 v = ((const float2*)(X + (size_t)node * 128))[lane];
    float s = v.x + v.y;
    float sq = v.x * v.x + v.y * v.y;
    #pragma unroll
    for (int off = 32; off; off >>= 1) {
        s += __shfl_down(s, off);
        sq += __shfl_down(sq, off);
    }
    s = __shfl(s, 0);
    sq = __shfl(sq, 0);
    float mu = s * (1.0f / 128.0f);
    float var = sq * (1.0f / 128.0f) - mu * mu;
    float rs = rsqrtf(var + EPS_);
    float2 gg = ((const float2*)g)[lane];
    float2 bb = ((const float2*)b)[lane];
    float ox = fmaxf((v.x - mu) * rs * gg.x + bb.x, 0.f);
    float oy = fmaxf((v.y - mu) * rs * gg.y + bb.y, 0.f);
    uint_t packed = (uint_t)f2bf(ox) | ((uint_t)f2bf(oy) << 16);
    ((uint_t*)(Hout + (size_t)node * 128))[lane] = packed;
}

// ---------------------------------------------------------------------------
// Head: pred[i] = base + dot(h[i], W_out) + b_out. One wave per node.
// ---------------------------------------------------------------------------
__global__ __launch_bounds__(256) void head_dot(const ushort_t* __restrict__ Hh,
                                                const float* __restrict__ Wout,
                                                const float* __restrict__ bout,
                                                const float* __restrict__ base,
                                                float* __restrict__ pred) {
    int node = blockIdx.x * 4 + (threadIdx.x >> 6);
    int lane = threadIdx.x & 63;
    uint_t u = ((const uint_t*)(Hh + (size_t)node * 128))[lane];
    float2 w = ((const float2*)Wout)[lane];
    float s = bf2f(u & 0xffffu) * w.x + bf2f(u >> 16) * w.y;
    #pragma unroll
    for (int off = 32; off; off >>= 1) s += __shfl_down(s, off);
    if (lane == 0) pred[node] = s + bout[0] + base[0];
}

// ---------------------------------------------------------------------------
extern "C" void kernel_launch(void* const* d_in, const int* in_sizes, int n_in,
                              void* d_out, int out_size, void* d_ws, size_t ws_size,
                              hipStream_t stream) {
    const float* x_a    = (const float*)d_in[0];
    const float* x_w    = (const float*)d_in[1];
    const int*   eidx   = (const int*)d_in[2];
    const int*   etype  = (const int*)d_in[3];
    const float* W_in_a = (const float*)d_in[4];
    const float* b_in_a = (const float*)d_in[5];
    const float* W_in_w = (const float*)d_in[6];
    const float* b_in_w = (const float*)d_in[7];
    const float* W_rel  = (const float*)d_in[8];   // (L,R,128,128)
    const float* W_root = (const float*)d_in[9];   // (L,128,128)
    const float* b_conv = (const float*)d_in[10];  // (L,128)
    const float* ln_g   = (const float*)d_in[11];
    const float* ln_b   = (const float*)d_in[12];
    const float* W_out  = (const float*)d_in[13];  // (128,1)
    const float* b_out  = (const float*)d_in[14];
    const float* base   = (const float*)d_in[15];

    const int* src  = eidx;        // edge_index[0]
    const int* dstv = eidx + EE;   // edge_index[1]

    // ---- workspace layout, sized against the ACTUAL ws_size ----
    char* p = (char*)d_ws;
    ushort_t* h = (ushort_t*)p;  p += (size_t)NN * 128 * sizeof(ushort_t); // 67 MB
    float* out  = (float*)p;     p += (size_t)NN * 128 * sizeof(float);    // 134 MB
    float* inv  = (float*)p;     p += (size_t)RR * NN * sizeof(float);     // 4.2 MB
    int*   cnt  = (int*)p;       p += (size_t)RR * NN * sizeof(int);       // 4.2 MB
    float* y    = (float*)p;
    size_t used = (size_t)(p - (char*)d_ws);
    size_t rem  = (ws_size > used) ? (ws_size - used) : 0;
    size_t rows = rem / (128 * sizeof(float));
    if (rows > NN) rows = NN;
    rows &= ~(size_t)127;            // multiple of 128 (gemm tile)
    if (rows == 0) rows = 128;       // ws too small: best effort
    int nchunk = (int)((NN + rows - 1) / rows);

    hipMemsetAsync(cnt, 0, (size_t)RR * NN * sizeof(int), stream);
    count_edges<<<EE / 256, 256, 0, stream>>>(dstv, etype, cnt);
    make_inv<<<RR * NN / 256, 256, 0, stream>>>(cnt, inv);

    // input projections + ReLU -> h (bf16)
    gemm128<64, false, true, true, true><<<NA_ / 128, 256, 0, stream>>>(
        x_a, W_in_a, b_in_a, h);
    gemm128<64, false, true, true, true><<<NW_ / 128, 256, 0, stream>>>(
        x_w, W_in_w, b_in_w, h + (size_t)NA_ * 128);

    for (int l = 0; l < 2; l++) {
        // out = h @ W_root + b_conv (fp32)
        gemm128<128, true, false, true, false><<<NN / 128, 256, 0, stream>>>(
            h, W_root + (size_t)l * 128 * 128, b_conv + l * 128, out);
        for (int r = 0; r < RR; r++) {
            const float* Wr = W_rel + ((size_t)l * RR + r) * 128 * 128;
            for (int c = 0; c < nchunk; c++) {
                int row_lo = (int)((size_t)c * rows);
                int chunk_rows = (int)(((size_t)(NN - row_lo) < rows)
                                           ? (size_t)(NN - row_lo) : rows);
                // y = h[row_lo : row_lo+chunk_rows] @ W_rel[l][r]  (fp32)
                gemm128<128, true, false, false, false>
                    <<<chunk_rows / 128, 256, 0, stream>>>(
                        h + (size_t)row_lo * 128, Wr, nullptr, y);
                scatter_rel<<<EE / 8, 256, 0, stream>>>(
                    src, dstv, etype, y, inv, out, r, row_lo, row_lo + chunk_rows);
            }
        }
        ln_relu<<<NN / 4, 256, 0, stream>>>(out, ln_g + l * 128, ln_b + l * 128, h);
    }

    head_dot<<<NA_ / 4, 256, 0, stream>>>(h, W_out, b_out, base, (float*)d_out);
}

// Round 3
// 4290.696 us; speedup vs baseline: 1.2560x; 1.2560x over previous
//
#include <hip/hip_runtime.h>

#define NA_ 131072
#define NN  262144
#define EE  1048576
#define RR  4
#define EPS_ 1e-5f

typedef unsigned short ushort_t;
typedef unsigned int uint_t;
typedef __attribute__((ext_vector_type(8))) short bf16x8;
typedef __attribute__((ext_vector_type(4))) float f32x4;

__device__ __forceinline__ float bf2f(uint_t u16) {
    return __uint_as_float(u16 << 16);
}
__device__ __forceinline__ uint_t f2bf(float f) {
    uint_t x = __float_as_uint(f);
    return (x + 0x7fffu + ((x >> 16) & 1u)) >> 16;   // RNE
}

// ---------------------------------------------------------------------------
// MFMA GEMM: C[M x NCH*128] = opt_relu(A[M x K] @ B[K x NCH*128] (+ bias))
// A: fp32 (A_F32) or bf16, row-major. Btg: bf16, fragment-ready [n][k]
// (row n = output col, K contiguous). C: fp32 or bf16 (OUT_BF).
// Block: 256 thr = 4 waves (2x2 of 64x64). Tile 128(M) x 128(N) per chunk,
// whole K staged in LDS. 16x16x32 bf16 MFMA, fp32 accum.
// Verified layouts (m89/m120): A-frag A[m=lane&15][k=(lane>>4)*8+j],
// B-frag B[k][n=lane&15], C/D col=lane&15, row=(lane>>4)*4+reg.
// ---------------------------------------------------------------------------
template<int K, int NCH, bool A_F32, bool OUT_BF, bool BIAS, bool RELU>
__global__ __launch_bounds__(256) void mfma_gemm(const void* __restrict__ Av,
                                                 const short* __restrict__ Btg,
                                                 const float* __restrict__ bias,
                                                 void* __restrict__ Cv) {
    __shared__ short As[128][K + 8];
    __shared__ short Bs[128][K + 8];
    const int tid  = threadIdx.x;
    const int lane = tid & 63;
    const int l15  = lane & 15;
    const int q    = lane >> 4;
    const int wv   = tid >> 6;
    const int wr   = (wv >> 1) * 64;
    const int wc   = (wv & 1) * 64;
    const size_t blockRow = (size_t)blockIdx.x * 128;
    const int ldc = NCH * 128;

    // ---- stage A (128 x K) into LDS, converting to bf16 if needed ----
    constexpr int ITERS = (128 * K) / (256 * 8);
    #pragma unroll
    for (int it = 0; it < ITERS; it++) {
        int sidx = (it * 256 + tid) * 8;
        int row = sidx / K, col = sidx % K;
        uint4 u;
        if (A_F32) {
            const float* Ag = (const float*)Av + (blockRow + row) * K + col;
            float4 v0 = *(const float4*)Ag;
            float4 v1 = *(const float4*)(Ag + 4);
            u.x = f2bf(v0.x) | (f2bf(v0.y) << 16);
            u.y = f2bf(v0.z) | (f2bf(v0.w) << 16);
            u.z = f2bf(v1.x) | (f2bf(v1.y) << 16);
            u.w = f2bf(v1.z) | (f2bf(v1.w) << 16);
        } else {
            u = *(const uint4*)((const ushort_t*)Av + (blockRow + row) * K + col);
        }
        *(uint4*)&As[row][col] = u;
    }

    for (int c = 0; c < NCH; c++) {
        __syncthreads();   // As ready (c==0) / previous Bs consumers done
        #pragma unroll
        for (int it = 0; it < ITERS; it++) {
            int sidx = (it * 256 + tid) * 8;
            int row = sidx / K, col = sidx % K;
            uint4 u = *(const uint4*)(Btg + ((size_t)(c * 128 + row)) * K + col);
            *(uint4*)&Bs[row][col] = u;
        }
        __syncthreads();

        f32x4 acc[4][4];
        #pragma unroll
        for (int i = 0; i < 4; i++)
            #pragma unroll
            for (int j = 0; j < 4; j++) {
                acc[i][j][0] = 0.f; acc[i][j][1] = 0.f;
                acc[i][j][2] = 0.f; acc[i][j][3] = 0.f;
            }

        #pragma unroll
        for (int kk = 0; kk < K / 32; kk++) {
            bf16x8 af[4], bfr[4];
            #pragma unroll
            for (int i = 0; i < 4; i++)
                af[i] = *(const bf16x8*)&As[wr + i * 16 + l15][kk * 32 + q * 8];
            #pragma unroll
            for (int j = 0; j < 4; j++)
                bfr[j] = *(const bf16x8*)&Bs[wc + j * 16 + l15][kk * 32 + q * 8];
            #pragma unroll
            for (int i = 0; i < 4; i++)
                #pragma unroll
                for (int j = 0; j < 4; j++)
                    acc[i][j] = __builtin_amdgcn_mfma_f32_16x16x32_bf16(
                        af[i], bfr[j], acc[i][j], 0, 0, 0);
        }

        // ---- epilogue ----
        #pragma unroll
        for (int j = 0; j < 4; j++) {
            int gcol = c * 128 + wc + j * 16 + l15;
            float bv = BIAS ? bias[gcol] : 0.f;
            #pragma unroll
            for (int i = 0; i < 4; i++) {
                size_t rbase = blockRow + wr + i * 16 + q * 4;
                #pragma unroll
                for (int r = 0; r < 4; r++) {
                    float v = acc[i][j][r] + bv;
                    if (RELU) v = fmaxf(v, 0.f);
                    if (OUT_BF)
                        ((ushort_t*)Cv)[(rbase + r) * (size_t)ldc + gcol] =
                            (ushort_t)f2bf(v);
                    else
                        ((float*)Cv)[(rbase + r) * (size_t)ldc + gcol] = v;
                }
            }
        }
    }
}

// ---------------------------------------------------------------------------
// Convert all weights to fragment-ready bf16 [n][k] layout in one pass.
// wbuf (shorts): [wt_ina 128x64][wt_inw 128x64][l0: root 128x128, rel 512x128]
//                [l1: root, rel]
// ---------------------------------------------------------------------------
__global__ void prep_weights(const float* __restrict__ Wia,
                             const float* __restrict__ Wiw,
                             const float* __restrict__ Wroot,
                             const float* __restrict__ Wrel,
                             short* __restrict__ wt) {
    int e = blockIdx.x * 256 + threadIdx.x;
    const float* src; short* dst; int Kseg, loc;
    if (e < 8192)       { src = Wia; dst = wt;        Kseg = 64; loc = e; }
    else if (e < 16384) { src = Wiw; dst = wt + 8192; Kseg = 64; loc = e - 8192; }
    else {
        int t = e - 16384;       // 0 .. 163839
        int seg = t >> 14;       // 0..9 : l0{root,rel0..3}, l1{root,rel0..3}
        loc = t & 16383;
        Kseg = 128;
        int l = seg / 5, s5 = seg % 5;
        src = (s5 == 0) ? (Wroot + l * 16384)
                        : (Wrel + ((size_t)(l * 4 + (s5 - 1))) * 16384);
        dst = wt + 16384 + (size_t)seg * 16384;
    }
    int k = loc >> 7, n = loc & 127;       // src row-major [k][n], 128 cols
    dst[n * Kseg + k] = (short)f2bf(src[loc]);
}

// ---------------------------------------------------------------------------
__global__ void count_edges(const int* __restrict__ dstv,
                            const int* __restrict__ et,
                            int* __restrict__ cnt) {
    int e = blockIdx.x * 256 + threadIdx.x;
    if (e < EE) atomicAdd(&cnt[(size_t)et[e] * NN + dstv[e]], 1);
}

__global__ void make_inv(const int* __restrict__ cnt, float* __restrict__ inv) {
    int i = blockIdx.x * 256 + threadIdx.x;
    if (i < RR * NN) {
        int c = cnt[i];
        inv[i] = 1.0f / (float)(c > 1 ? c : 1);
    }
}

// ---------------------------------------------------------------------------
// Single-pass scatter over ALL relations: out[dst] += y[src][et*128+:] * inv
// y: bf16 [rows][512] (4 relation blocks). 32 lanes/edge, 8 edges/block.
// ---------------------------------------------------------------------------
__global__ __launch_bounds__(256) void scatter_all(const int* __restrict__ srcv,
                                                   const int* __restrict__ dstv,
                                                   const int* __restrict__ et,
                                                   const ushort_t* __restrict__ y,
                                                   const float* __restrict__ inv,
                                                   float* __restrict__ out,
                                                   int row_lo, int row_hi) {
    int e = blockIdx.x * 8 + (threadIdx.x >> 5);
    int lane = threadIdx.x & 31;
    int s = srcv[e];
    if (s < row_lo || s >= row_hi) return;
    int d = dstv[e], r = et[e];
    float w = inv[(size_t)r * NN + d];
    uint2 u = ((const uint2*)(y + ((size_t)(s - row_lo) * 512 + r * 128)))[lane];
    float* o = out + (size_t)d * 128 + lane * 4;
    atomicAdd(o + 0, bf2f(u.x & 0xffffu) * w);
    atomicAdd(o + 1, bf2f(u.x >> 16) * w);
    atomicAdd(o + 2, bf2f(u.y & 0xffffu) * w);
    atomicAdd(o + 3, bf2f(u.y >> 16) * w);
}

// ---------------------------------------------------------------------------
__global__ __launch_bounds__(256) void ln_relu(const float* __restrict__ X,
                                               const float* __restrict__ g,
                                               const float* __restrict__ b,
                                               ushort_t* __restrict__ Hout) {
    int node = blockIdx.x * 4 + (threadIdx.x >> 6);
    int lane = threadIdx.x & 63;
    float2 v = ((const float2*)(X + (size_t)node * 128))[lane];
    float s = v.x + v.y;
    float sq = v.x * v.x + v.y * v.y;
    #pragma unroll
    for (int off = 32; off; off >>= 1) {
        s += __shfl_down(s, off);
        sq += __shfl_down(sq, off);
    }
    s = __shfl(s, 0);
    sq = __shfl(sq, 0);
    float mu = s * (1.0f / 128.0f);
    float var = sq * (1.0f / 128.0f) - mu * mu;
    float rs = rsqrtf(var + EPS_);
    float2 gg = ((const float2*)g)[lane];
    float2 bb = ((const float2*)b)[lane];
    float ox = fmaxf((v.x - mu) * rs * gg.x + bb.x, 0.f);
    float oy = fmaxf((v.y - mu) * rs * gg.y + bb.y, 0.f);
    ((uint_t*)(Hout + (size_t)node * 128))[lane] =
        f2bf(ox) | (f2bf(oy) << 16);
}

// ---------------------------------------------------------------------------
__global__ __launch_bounds__(256) void head_dot(const ushort_t* __restrict__ Hh,
                                                const float* __restrict__ Wout,
                                                const float* __restrict__ bout,
                                                const float* __restrict__ base,
                                                float* __restrict__ pred) {
    int node = blockIdx.x * 4 + (threadIdx.x >> 6);
    int lane = threadIdx.x & 63;
    uint_t u = ((const uint_t*)(Hh + (size_t)node * 128))[lane];
    float2 w = ((const float2*)Wout)[lane];
    float s = bf2f(u & 0xffffu) * w.x + bf2f(u >> 16) * w.y;
    #pragma unroll
    for (int off = 32; off; off >>= 1) s += __shfl_down(s, off);
    if (lane == 0) pred[node] = s + bout[0] + base[0];
}

// ---------------------------------------------------------------------------
extern "C" void kernel_launch(void* const* d_in, const int* in_sizes, int n_in,
                              void* d_out, int out_size, void* d_ws, size_t ws_size,
                              hipStream_t stream) {
    const float* x_a    = (const float*)d_in[0];
    const float* x_w    = (const float*)d_in[1];
    const int*   eidx   = (const int*)d_in[2];
    const int*   etype  = (const int*)d_in[3];
    const float* W_in_a = (const float*)d_in[4];
    const float* b_in_a = (const float*)d_in[5];
    const float* W_in_w = (const float*)d_in[6];
    const float* b_in_w = (const float*)d_in[7];
    const float* W_rel  = (const float*)d_in[8];   // (2,4,128,128)
    const float* W_root = (const float*)d_in[9];   // (2,128,128)
    const float* b_conv = (const float*)d_in[10];  // (2,128)
    const float* ln_g   = (const float*)d_in[11];
    const float* ln_b   = (const float*)d_in[12];
    const float* W_out  = (const float*)d_in[13];  // (128,1)
    const float* b_out  = (const float*)d_in[14];
    const float* base   = (const float*)d_in[15];

    const int* src  = eidx;
    const int* dstv = eidx + EE;

    // ---- workspace layout (all offsets 256B-aligned) ----
    char* p = (char*)d_ws;
    ushort_t* h  = (ushort_t*)p; p += (size_t)NN * 128 * sizeof(ushort_t); // 67 MB
    float* out   = (float*)p;    p += (size_t)NN * 128 * sizeof(float);    // 134 MB
    float* inv   = (float*)p;    p += (size_t)RR * NN * sizeof(float);     // 4.2 MB
    int*   cnt   = (int*)p;      p += (size_t)RR * NN * sizeof(int);       // 4.2 MB
    short* wbuf  = (short*)p;    p += (size_t)180224 * sizeof(short);      // 0.36 MB
    ushort_t* y  = (ushort_t*)p;                                           // chunked
    size_t used = (size_t)(p - (char*)d_ws);
    size_t rem  = (ws_size > used) ? (ws_size - used) : 0;
    size_t rows = rem / (512 * sizeof(ushort_t));   // y row = 512 bf16
    if (rows > NN) rows = NN;
    rows &= ~(size_t)127;
    if (rows == 0) rows = 128;   // ws too small: best effort
    int nchunk = (int)((NN + rows - 1) / rows);

    short* wt_ina = wbuf;
    short* wt_inw = wbuf + 8192;
    auto wt_root = [&](int l) { return wbuf + 16384 + (size_t)(l * 5) * 16384; };
    auto wt_rel  = [&](int l) { return wbuf + 16384 + (size_t)(l * 5 + 1) * 16384; };

    hipMemsetAsync(cnt, 0, (size_t)RR * NN * sizeof(int), stream);
    count_edges<<<EE / 256, 256, 0, stream>>>(dstv, etype, cnt);
    make_inv<<<RR * NN / 256, 256, 0, stream>>>(cnt, inv);
    prep_weights<<<704, 256, 0, stream>>>(W_in_a, W_in_w, W_root, W_rel, wbuf);

    // input projections + ReLU -> h (bf16)
    mfma_gemm<64, 1, true, true, true, true><<<NA_ / 128, 256, 0, stream>>>(
        x_a, wt_ina, b_in_a, h);
    mfma_gemm<64, 1, true, true, true, true><<<NA_ / 128, 256, 0, stream>>>(
        x_w, wt_inw, b_in_w, h + (size_t)NA_ * 128);

    for (int l = 0; l < 2; l++) {
        // out = h @ W_root + b_conv  (fp32)
        mfma_gemm<128, 1, false, false, true, false><<<NN / 128, 256, 0, stream>>>(
            h, wt_root(l), b_conv + l * 128, out);
        for (int c = 0; c < nchunk; c++) {
            int row_lo = (int)((size_t)c * rows);
            int chunk_rows = (int)(((size_t)(NN - row_lo) < rows)
                                       ? (size_t)(NN - row_lo) : rows);
            // y = h[chunk] @ [W_rel r0|r1|r2|r3]  (bf16, 512 cols)
            mfma_gemm<128, 4, false, true, false, false>
                <<<chunk_rows / 128, 256, 0, stream>>>(
                    h + (size_t)row_lo * 128, wt_rel(l), nullptr, y);
            scatter_all<<<EE / 8, 256, 0, stream>>>(
                src, dstv, etype, y, inv, out, row_lo, row_lo + chunk_rows);
        }
        ln_relu<<<NN / 4, 256, 0, stream>>>(out, ln_g + l * 128, ln_b + l * 128, h);
    }

    head_dot<<<NA_ / 4, 256, 0, stream>>>(h, W_out, b_out, base, (float*)d_out);
}

// Round 4
// 821.587 us; speedup vs baseline: 6.5592x; 5.2225x over previous
//
#include <hip/hip_runtime.h>

#define NA_ 131072
#define NN  262144
#define EE  1048576
#define RR  4
#define EPS_ 1e-5f

typedef unsigned short ushort_t;
typedef unsigned int uint_t;
typedef __attribute__((ext_vector_type(8))) short bf16x8;
typedef __attribute__((ext_vector_type(4))) float f32x4;

__device__ __forceinline__ float bf2f(uint_t u16) {
    return __uint_as_float(u16 << 16);
}
__device__ __forceinline__ uint_t f2bf(float f) {
    uint_t x = __float_as_uint(f);
    return (x + 0x7fffu + ((x >> 16) & 1u)) >> 16;   // RNE
}

// ---------------------------------------------------------------------------
// Input projection GEMM (proven in r3): C[M x 128] = relu(A[M x 64] @ B + b)
// A fp32 row-major, Btg bf16 fragment-ready [n][64], C bf16.
// ---------------------------------------------------------------------------
__global__ __launch_bounds__(256) void proj_gemm(const float* __restrict__ A,
                                                 const short* __restrict__ Btg,
                                                 const float* __restrict__ bias,
                                                 ushort_t* __restrict__ C) {
    const int K = 64;
    __shared__ short As[128][K + 8];
    __shared__ short Bs[128][K + 8];
    const int tid  = threadIdx.x;
    const int lane = tid & 63;
    const int l15  = lane & 15;
    const int q    = lane >> 4;
    const int wv   = tid >> 6;
    const int wr   = (wv >> 1) * 64;
    const int wc   = (wv & 1) * 64;
    const size_t blockRow = (size_t)blockIdx.x * 128;

    #pragma unroll
    for (int it = 0; it < 4; it++) {
        int sidx = (it * 256 + tid) * 8;
        int row = sidx / K, col = sidx % K;
        const float* Ag = A + (blockRow + row) * K + col;
        float4 v0 = *(const float4*)Ag;
        float4 v1 = *(const float4*)(Ag + 4);
        uint4 u;
        u.x = f2bf(v0.x) | (f2bf(v0.y) << 16);
        u.y = f2bf(v0.z) | (f2bf(v0.w) << 16);
        u.z = f2bf(v1.x) | (f2bf(v1.y) << 16);
        u.w = f2bf(v1.z) | (f2bf(v1.w) << 16);
        *(uint4*)&As[row][col] = u;
        *(uint4*)&Bs[row][col] = *(const uint4*)(Btg + (size_t)row * K + col);
    }
    __syncthreads();

    f32x4 acc[4][4];
    #pragma unroll
    for (int i = 0; i < 4; i++)
        #pragma unroll
        for (int j = 0; j < 4; j++) {
            acc[i][j][0] = 0.f; acc[i][j][1] = 0.f;
            acc[i][j][2] = 0.f; acc[i][j][3] = 0.f;
        }

    #pragma unroll
    for (int kk = 0; kk < 2; kk++) {
        bf16x8 af[4], bfr[4];
        #pragma unroll
        for (int i = 0; i < 4; i++)
            af[i] = *(const bf16x8*)&As[wr + i * 16 + l15][kk * 32 + q * 8];
        #pragma unroll
        for (int j = 0; j < 4; j++)
            bfr[j] = *(const bf16x8*)&Bs[wc + j * 16 + l15][kk * 32 + q * 8];
        #pragma unroll
        for (int i = 0; i < 4; i++)
            #pragma unroll
            for (int j = 0; j < 4; j++)
                acc[i][j] = __builtin_amdgcn_mfma_f32_16x16x32_bf16(
                    af[i], bfr[j], acc[i][j], 0, 0, 0);
    }

    #pragma unroll
    for (int j = 0; j < 4; j++) {
        int gcol = wc + j * 16 + l15;
        float bv = bias[gcol];
        #pragma unroll
        for (int i = 0; i < 4; i++) {
            size_t rbase = blockRow + wr + i * 16 + q * 4;
            #pragma unroll
            for (int r = 0; r < 4; r++) {
                float v = fmaxf(acc[i][j][r] + bv, 0.f);
                C[(rbase + r) * 128 + gcol] = (ushort_t)f2bf(v);
            }
        }
    }
}

// ---------------------------------------------------------------------------
// Weight prep: bf16 fragment-ready layouts.
// wbuf: [wt_ina 128x64][wt_inw 128x64][l0: 128 n x 640 k][l1: 128 x 640]
// layer k-order: [rel0 | rel1 | rel2 | rel3 | root]
// ---------------------------------------------------------------------------
__global__ void prep_weights(const float* __restrict__ Wia,
                             const float* __restrict__ Wiw,
                             const float* __restrict__ Wroot,
                             const float* __restrict__ Wrel,
                             short* __restrict__ wt) {
    int e = blockIdx.x * 256 + threadIdx.x;
    if (e < 8192) {
        int k = e >> 7, n = e & 127;
        wt[n * 64 + k] = (short)f2bf(Wia[e]);
    } else if (e < 16384) {
        int t = e - 8192;
        int k = t >> 7, n = t & 127;
        wt[8192 + n * 64 + k] = (short)f2bf(Wiw[t]);
    } else {
        int t = e - 16384;           // 0 .. 163839
        int l = t / 81920;
        int loc = t % 81920;
        int n = loc / 640;
        int k = loc % 640;
        float val;
        if (k < 512) {
            int r = k >> 7, kk = k & 127;
            val = Wrel[(((size_t)l * 4 + r) * 128 + kk) * 128 + n];
        } else {
            int kk = k - 512;
            val = Wroot[((size_t)l * 128 + kk) * 128 + n];
        }
        wt[16384 + (size_t)l * 81920 + n * 640 + k] = (short)f2bf(val);
    }
}

// ---------------------------------------------------------------------------
// CSR build
// ---------------------------------------------------------------------------
__global__ void count_edges(const int* __restrict__ dstv,
                            const int* __restrict__ et,
                            int* __restrict__ cnt) {
    int e = blockIdx.x * 256 + threadIdx.x;
    if (e < EE) atomicAdd(&cnt[(size_t)et[e] * NN + dstv[e]], 1);
}

__global__ void make_inv(const int* __restrict__ cnt, float* __restrict__ inv) {
    int i = blockIdx.x * 256 + threadIdx.x;
    if (i < RR * NN) {
        int c = cnt[i];
        inv[i] = 1.0f / (float)(c > 1 ? c : 1);
    }
}

__global__ void deg_from_cnt(const int* __restrict__ cnt, int* __restrict__ deg) {
    int i = blockIdx.x * 256 + threadIdx.x;
    if (i < NN)
        deg[i] = cnt[i] + cnt[NN + i] + cnt[2 * NN + i] + cnt[3 * NN + i];
}

// per-block (256) exclusive scan; block totals to bsum
__global__ void scan1(const int* __restrict__ deg, int* __restrict__ offs,
                      int* __restrict__ bsum) {
    __shared__ int lds[256];
    int tid = threadIdx.x;
    int i = blockIdx.x * 256 + tid;
    int v = deg[i];
    int incl = v;
    lds[tid] = incl;
    __syncthreads();
    for (int off = 1; off < 256; off <<= 1) {
        int t = (tid >= off) ? lds[tid - off] : 0;
        __syncthreads();
        incl += t;
        lds[tid] = incl;
        __syncthreads();
    }
    offs[i] = incl - v;
    if (tid == 255) bsum[blockIdx.x] = incl;
}

// single block: exclusive scan of 1024 block sums in place
__global__ void scan_bsum(int* __restrict__ bsum) {
    __shared__ int lds[256];
    int tid = threadIdx.x;
    int t0 = bsum[tid * 4 + 0], t1 = bsum[tid * 4 + 1];
    int t2 = bsum[tid * 4 + 2], t3 = bsum[tid * 4 + 3];
    int s = t0 + t1 + t2 + t3;
    int incl = s;
    lds[tid] = incl;
    __syncthreads();
    for (int off = 1; off < 256; off <<= 1) {
        int t = (tid >= off) ? lds[tid - off] : 0;
        __syncthreads();
        incl += t;
        lds[tid] = incl;
        __syncthreads();
    }
    int e = incl - s;
    bsum[tid * 4 + 0] = e;
    bsum[tid * 4 + 1] = e + t0;
    bsum[tid * 4 + 2] = e + t0 + t1;
    bsum[tid * 4 + 3] = e + t0 + t1 + t2;
}

__global__ void scan_add(int* __restrict__ offs, const int* __restrict__ bsum,
                         int* __restrict__ cursor) {
    int i = blockIdx.x * 256 + threadIdx.x;
    int v = offs[i] + bsum[blockIdx.x];
    offs[i] = v;
    cursor[i] = v;
    if (i == 0) offs[NN] = EE;
}

__global__ void place_edges(const int* __restrict__ srcv,
                            const int* __restrict__ dstv,
                            const int* __restrict__ et,
                            int* __restrict__ cursor,
                            uint_t* __restrict__ pk) {
    int e = blockIdx.x * 256 + threadIdx.x;
    if (e < EE) {
        int pos = atomicAdd(&cursor[dstv[e]], 1);
        pk[pos] = (uint_t)srcv[e] | ((uint_t)et[e] << 18);
    }
}

// ---------------------------------------------------------------------------
// Pull aggregation: one wave per dst node. M[d-lo] = [mean_0|..|mean_3] bf16.
// ---------------------------------------------------------------------------
__global__ __launch_bounds__(256) void agg_means(const uint_t* __restrict__ pk,
                                                 const int* __restrict__ offs,
                                                 const ushort_t* __restrict__ hold,
                                                 const float* __restrict__ inv,
                                                 ushort_t* __restrict__ M,
                                                 int lo) {
    int d = lo + blockIdx.x * 4 + (threadIdx.x >> 6);
    int lane = threadIdx.x & 63;
    float2 a0 = {0.f, 0.f}, a1 = {0.f, 0.f}, a2 = {0.f, 0.f}, a3 = {0.f, 0.f};
    int beg = offs[d], end = offs[d + 1];
    for (int e = beg; e < end; e++) {
        uint_t p = pk[e];
        int s = p & 0x3FFFF;
        int r = p >> 18;
        uint_t hv = ((const uint_t*)(hold + (size_t)s * 128))[lane];
        float x = bf2f(hv & 0xffffu), yv = bf2f(hv >> 16);
        if (r == 0)      { a0.x += x; a0.y += yv; }
        else if (r == 1) { a1.x += x; a1.y += yv; }
        else if (r == 2) { a2.x += x; a2.y += yv; }
        else             { a3.x += x; a3.y += yv; }
    }
    float w0 = inv[d], w1 = inv[NN + d], w2 = inv[2 * NN + d], w3 = inv[3 * NN + d];
    uint_t* Mrow = (uint_t*)(M + (size_t)(d - lo) * 512);
    Mrow[lane]        = f2bf(a0.x * w0) | (f2bf(a0.y * w0) << 16);
    Mrow[64 + lane]   = f2bf(a1.x * w1) | (f2bf(a1.y * w1) << 16);
    Mrow[128 + lane]  = f2bf(a2.x * w2) | (f2bf(a2.y * w2) << 16);
    Mrow[192 + lane]  = f2bf(a3.x * w3) | (f2bf(a3.y * w3) << 16);
}

// ---------------------------------------------------------------------------
// Fused layer GEMM: h_new = relu(LN([M | h_old] @ [Wrel0..3;Wroot] + b_conv))
// K = 640 (5 x BK=128), tile 128x128, 4 waves (2x2 of 64x64), LN in epilogue.
// ---------------------------------------------------------------------------
__global__ __launch_bounds__(256) void layer_gemm_ln(
    const ushort_t* __restrict__ M,      // [chunk_rows][512]
    const ushort_t* __restrict__ hold,   // [NN][128]
    const short* __restrict__ Btg,       // [128 n][640 k]
    const float* __restrict__ bconv,
    const float* __restrict__ lng,
    const float* __restrict__ lnb,
    ushort_t* __restrict__ hnew,
    int lo) {
    __shared__ short As[128][136];
    __shared__ short Bs[128][136];
    __shared__ float lds_s[128][2];
    __shared__ float lds_q[128][2];

    const int tid  = threadIdx.x;
    const int lane = tid & 63;
    const int l15  = lane & 15;
    const int q    = lane >> 4;
    const int wv   = tid >> 6;
    const int wr   = (wv >> 1) * 64;
    const int wc   = (wv & 1) * 64;
    const int blockRowL = blockIdx.x * 128;

    f32x4 acc[4][4];
    #pragma unroll
    for (int i = 0; i < 4; i++)
        #pragma unroll
        for (int j = 0; j < 4; j++) {
            acc[i][j][0] = 0.f; acc[i][j][1] = 0.f;
            acc[i][j][2] = 0.f; acc[i][j][3] = 0.f;
        }

    for (int kc = 0; kc < 5; kc++) {
        __syncthreads();
        #pragma unroll
        for (int it = 0; it < 8; it++) {
            int idx = (it * 256 + tid) * 8;
            int row = idx >> 7, col = idx & 127;
            uint4 u;
            if (kc < 4)
                u = *(const uint4*)(M + ((size_t)(blockRowL + row) * 512
                                         + kc * 128 + col));
            else
                u = *(const uint4*)(hold + ((size_t)(lo + blockRowL + row) * 128
                                            + col));
            *(uint4*)&As[row][col] = u;
            *(uint4*)&Bs[row][col] =
                *(const uint4*)(Btg + ((size_t)row * 640 + kc * 128 + col));
        }
        __syncthreads();
        #pragma unroll
        for (int kk = 0; kk < 4; kk++) {
            bf16x8 af[4], bfr[4];
            #pragma unroll
            for (int i = 0; i < 4; i++)
                af[i] = *(const bf16x8*)&As[wr + i * 16 + l15][kk * 32 + q * 8];
            #pragma unroll
            for (int j = 0; j < 4; j++)
                bfr[j] = *(const bf16x8*)&Bs[wc + j * 16 + l15][kk * 32 + q * 8];
            #pragma unroll
            for (int i = 0; i < 4; i++)
                #pragma unroll
                for (int j = 0; j < 4; j++)
                    acc[i][j] = __builtin_amdgcn_mfma_f32_16x16x32_bf16(
                        af[i], bfr[j], acc[i][j], 0, 0, 0);
        }
    }

    // ---- epilogue: + b_conv, LayerNorm over the 128 cols, affine, ReLU ----
    float bj[4], gj[4], bbj[4];
    #pragma unroll
    for (int j = 0; j < 4; j++) {
        int col = wc + j * 16 + l15;
        bj[j]  = bconv[col];
        gj[j]  = lng[col];
        bbj[j] = lnb[col];
    }
    #pragma unroll
    for (int i = 0; i < 4; i++)
        #pragma unroll
        for (int j = 0; j < 4; j++)
            #pragma unroll
            for (int r = 0; r < 4; r++) acc[i][j][r] += bj[j];

    float ps[4][4], pq[4][4];   // [i][reg]
    #pragma unroll
    for (int i = 0; i < 4; i++)
        #pragma unroll
        for (int r = 0; r < 4; r++) {
            float s = 0.f, qq = 0.f;
            #pragma unroll
            for (int j = 0; j < 4; j++) {
                float v = acc[i][j][r];
                s += v;
                qq += v * v;
            }
            ps[i][r] = s;
            pq[i][r] = qq;
        }
    #pragma unroll
    for (int m = 1; m <= 8; m <<= 1)
        #pragma unroll
        for (int i = 0; i < 4; i++)
            #pragma unroll
            for (int r = 0; r < 4; r++) {
                ps[i][r] += __shfl_xor(ps[i][r], m);
                pq[i][r] += __shfl_xor(pq[i][r], m);
            }

    if (l15 == 0) {
        #pragma unroll
        for (int i = 0; i < 4; i++)
            #pragma unroll
            for (int r = 0; r < 4; r++) {
                int row = wr + i * 16 + q * 4 + r;
                lds_s[row][wv & 1] = ps[i][r];
                lds_q[row][wv & 1] = pq[i][r];
            }
    }
    __syncthreads();

    #pragma unroll
    for (int i = 0; i < 4; i++)
        #pragma unroll
        for (int r = 0; r < 4; r++) {
            int row = wr + i * 16 + q * 4 + r;
            float sum = lds_s[row][0] + lds_s[row][1];
            float sq  = lds_q[row][0] + lds_q[row][1];
            float mu  = sum * (1.0f / 128.0f);
            float var = sq * (1.0f / 128.0f) - mu * mu;
            float rs  = rsqrtf(var + EPS_);
            size_t gr = (size_t)(lo + blockRowL + row) * 128;
            #pragma unroll
            for (int j = 0; j < 4; j++) {
                float v = (acc[i][j][r] - mu) * rs * gj[j] + bbj[j];
                v = fmaxf(v, 0.f);
                hnew[gr + wc + j * 16 + l15] = (ushort_t)f2bf(v);
            }
        }
}

// ---------------------------------------------------------------------------
__global__ __launch_bounds__(256) void head_dot(const ushort_t* __restrict__ Hh,
                                                const float* __restrict__ Wout,
                                                const float* __restrict__ bout,
                                                const float* __restrict__ base,
                                                float* __restrict__ pred) {
    int node = blockIdx.x * 4 + (threadIdx.x >> 6);
    int lane = threadIdx.x & 63;
    uint_t u = ((const uint_t*)(Hh + (size_t)node * 128))[lane];
    float2 w = ((const float2*)Wout)[lane];
    float s = bf2f(u & 0xffffu) * w.x + bf2f(u >> 16) * w.y;
    #pragma unroll
    for (int off = 32; off; off >>= 1) s += __shfl_down(s, off);
    if (lane == 0) pred[node] = s + bout[0] + base[0];
}

// ---------------------------------------------------------------------------
extern "C" void kernel_launch(void* const* d_in, const int* in_sizes, int n_in,
                              void* d_out, int out_size, void* d_ws, size_t ws_size,
                              hipStream_t stream) {
    const float* x_a    = (const float*)d_in[0];
    const float* x_w    = (const float*)d_in[1];
    const int*   eidx   = (const int*)d_in[2];
    const int*   etype  = (const int*)d_in[3];
    const float* W_in_a = (const float*)d_in[4];
    const float* b_in_a = (const float*)d_in[5];
    const float* W_in_w = (const float*)d_in[6];
    const float* b_in_w = (const float*)d_in[7];
    const float* W_rel  = (const float*)d_in[8];
    const float* W_root = (const float*)d_in[9];
    const float* b_conv = (const float*)d_in[10];
    const float* ln_g   = (const float*)d_in[11];
    const float* ln_b   = (const float*)d_in[12];
    const float* W_out  = (const float*)d_in[13];
    const float* b_out  = (const float*)d_in[14];
    const float* base   = (const float*)d_in[15];

    const int* src  = eidx;
    const int* dstv = eidx + EE;

    // ---- workspace layout ----
    char* p = (char*)d_ws;
    auto alloc = [&](size_t bytes) {
        char* q = p;
        p += (bytes + 255) & ~(size_t)255;
        return q;
    };
    ushort_t* hA   = (ushort_t*)alloc((size_t)NN * 128 * 2);   // 67.1 MB
    ushort_t* hB   = (ushort_t*)alloc((size_t)NN * 128 * 2);   // 67.1 MB
    float*    inv  = (float*)alloc((size_t)RR * NN * 4);       // 4.2 MB
    int*      cnt  = (int*)alloc((size_t)RR * NN * 4);         // 4.2 MB
    uint_t*   pk   = (uint_t*)alloc((size_t)EE * 4);           // 4.2 MB
    short*    wbuf = (short*)alloc((size_t)180224 * 2);        // 0.36 MB
    int*      curs = (int*)alloc((size_t)NN * 4);              // 1.05 MB
    int*      bsum = (int*)alloc((size_t)1024 * 4);
    int*      offs = (int*)alloc((size_t)(NN + 1) * 4);        // 1.05 MB
    ushort_t* M    = (ushort_t*)p;                             // chunked

    size_t used = (size_t)(p - (char*)d_ws);
    size_t rem  = (ws_size > used) ? (ws_size - used) : 0;
    size_t rows = rem / (512 * sizeof(ushort_t));
    if (rows > NN) rows = NN;
    rows &= ~(size_t)127;
    if (rows == 0) rows = 128;
    int nchunk = (int)((NN + rows - 1) / rows);

    short* wt_ina = wbuf;
    short* wt_inw = wbuf + 8192;
    auto wt_layer = [&](int l) { return wbuf + 16384 + (size_t)l * 81920; };

    // ---- CSR + inv ----
    hipMemsetAsync(cnt, 0, (size_t)RR * NN * sizeof(int), stream);
    count_edges<<<EE / 256, 256, 0, stream>>>(dstv, etype, cnt);
    make_inv<<<RR * NN / 256, 256, 0, stream>>>(cnt, inv);
    deg_from_cnt<<<NN / 256, 256, 0, stream>>>(cnt, curs);     // deg -> curs
    scan1<<<NN / 256, 256, 0, stream>>>(curs, offs, bsum);
    scan_bsum<<<1, 256, 0, stream>>>(bsum);
    scan_add<<<NN / 256, 256, 0, stream>>>(offs, bsum, curs);
    place_edges<<<EE / 256, 256, 0, stream>>>(src, dstv, etype, curs, pk);

    prep_weights<<<704, 256, 0, stream>>>(W_in_a, W_in_w, W_root, W_rel, wbuf);

    // ---- input projections ----
    proj_gemm<<<NA_ / 128, 256, 0, stream>>>(x_a, wt_ina, b_in_a, hA);
    proj_gemm<<<NA_ / 128, 256, 0, stream>>>(x_w, wt_inw, b_in_w,
                                             hA + (size_t)NA_ * 128);

    // ---- layers ----
    ushort_t* hc = hA;
    ushort_t* hn = hB;
    for (int l = 0; l < 2; l++) {
        for (int c = 0; c < nchunk; c++) {
            int lo = (int)((size_t)c * rows);
            int cr = (int)(((size_t)(NN - lo) < rows) ? (size_t)(NN - lo) : rows);
            agg_means<<<cr / 4, 256, 0, stream>>>(pk, offs, hc, inv, M, lo);
            layer_gemm_ln<<<cr / 128, 256, 0, stream>>>(
                M, hc, wt_layer(l), b_conv + l * 128, ln_g + l * 128,
                ln_b + l * 128, hn, lo);
        }
        ushort_t* t = hc; hc = hn; hn = t;
    }

    head_dot<<<NA_ / 4, 256, 0, stream>>>(hc, W_out, b_out, base, (float*)d_out);
}